// Round 12
// baseline (266.456 us; speedup 1.0000x reference)
//
#include <hip/hip_runtime.h>

// DCI Neural-ODE battery rollout. B=1024 batteries, H=1024 serial steps.
// 2 waves per battery. The ONLY true serial dependence is soc -> MLP -> Q -> soc;
// v1 is a LINEAR recurrence (v1' = a*v1 + b) given params => parallel scan.
//   Wave A (serial, minimal): hidden layer -> chain-3 reduction (6 DPP) ->
//     softplus -> invQ -> soc update. Hands {socCarry, socPost} per step.
//   Wave B (chunk c-1, lane = time-step): param MLP recompute for R0/R1/C1
//     (per-lane dot products, LDS-broadcast weights), v1 Kogge-Stone scan
//     (6 shfl_up levels, chunk carry via readlane 63), resid MLP, OCV,
//     V assembly, store.
// Weights pre-scaled into exp2/log2 domain (K2 = 2log2e for tanh, KL = log2e
// for softplus-in-log2).

#define NB 1024
#define HT 1024
#define HIDN 128
#define NCHUNK 16

#define K2  2.885390081777927f   // 2*log2(e)
#define KL  1.4426950408889634f  // log2(e)
#define LN2 0.6931471805599453f
#define EPSP 1e-6f
#define SOCK -2.77777777777778e-4f  // -1/3600

__device__ __forceinline__ float readlane_f(float v, int lane) {
    int r = __builtin_amdgcn_readlane(__builtin_bit_cast(int, v), lane);
    return __builtin_bit_cast(float, r);
}

template <int CTRL, int RMASK>
__device__ __forceinline__ float dpp_add(float x) {
    int s = __builtin_amdgcn_update_dpp(0, __builtin_bit_cast(int, x),
                                        CTRL, RMASK, 0xF, true);
    return x + __builtin_bit_cast(float, s);
}

// tanh in pre-scaled domain: z already = 2*log2(e)*x
__device__ __forceinline__ float tanh_ps(float z) {
    float t = __builtin_amdgcn_exp2f(z);
    float r = __builtin_amdgcn_rcpf(t + 1.0f);
    return fmaf(-2.0f, r, 1.0f);
}

__global__ __launch_bounds__(128, 1) void rollout_kernel(
    const float* __restrict__ Iin, const float* __restrict__ Tzin,
    const float* __restrict__ soc0,
    const float* __restrict__ W1p, const float* __restrict__ b1p,
    const float* __restrict__ W2p, const float* __restrict__ b2p,
    const float* __restrict__ W1r, const float* __restrict__ b1r,
    const float* __restrict__ W2r, const float* __restrict__ b2r,
    float* __restrict__ out)
{
    const int b    = blockIdx.x;
    const int wid  = threadIdx.x >> 6;
    const int lane = threadIdx.x & 63;

    __shared__ float2 handBuf[2][64];  // {socCarry, socPost} per step
    __shared__ float4 pcoefS[128];     // param hidden unit j: {w0,w1,w2,b}*K2
    __shared__ float4 poutS[128];      // {W2p[j][0..2]}*KL, .w unused
    __shared__ float4 rcoefS[64];      // resid hidden unit coeffs *K2
    __shared__ float  w2rS[64];

    const float* Ib = Iin  + (size_t)b * HT;
    const float* Tb = Tzin + (size_t)b * HT;
    float*       Ob = out  + (size_t)b * HT;

    // ---------------- wave-A registers (serial soc loop) ----------------
    float w1pa0=0,w1pa1=0,w1pa2=0,bpa=0, w1pb0=0,w1pb1=0,w1pb2=0,bpb=0;
    float w2pa3=0, w2pb3=0, biasQ=0;
    float socv=0, Inext=0, Tnext=0;

    // ---------------- wave-B registers ----------------
    float v1c = 0.0f;                  // v1 at current chunk start
    float bias0=0, bias1=0, bias2=0, b2rr=0;

    if (wid == 0) {
        const int ja = lane, jb = lane + 64;
        w1pa0 = W1p[0*HIDN+ja]*K2; w1pa1 = W1p[1*HIDN+ja]*K2; w1pa2 = W1p[2*HIDN+ja]*K2;
        w1pb0 = W1p[0*HIDN+jb]*K2; w1pb1 = W1p[1*HIDN+jb]*K2; w1pb2 = W1p[2*HIDN+jb]*K2;
        bpa = b1p[ja]*K2; bpb = b1p[jb]*K2;
        w2pa3 = W2p[ja*4+3]*KL; w2pb3 = W2p[jb*4+3]*KL;   // Q column only
        biasQ = b2p[3]*KL;

        socv = soc0[b];
        unsigned u = __builtin_bit_cast(unsigned, socv);
        if ((u & 0x7FFFFFFFu) > 0x7F800000u) socv = 0.8f;   // NaN -> 0.8
        Inext = Ib[lane];
        Tnext = Tb[lane];
    } else {
        bias0 = b2p[0]*KL; bias1 = b2p[1]*KL; bias2 = b2p[2]*KL;
        b2rr  = b2r[0];
    }

    for (int c = 0; c <= NCHUNK; ++c) {
        if (wid == 0) {
            if (c < NCHUNK) {
                const float Ibuf = Inext;
                const float Tbuf = Tnext;
                const int t1 = (c + 1) * 64;
                if (t1 < HT) { Inext = Ib[t1 + lane]; Tnext = Tb[t1 + lane]; }

                float2 hand = make_float2(0.f, 0.f);
                #pragma unroll 8
                for (int s = 0; s < 64; ++s) {
                    const float It  = readlane_f(Ibuf, s);
                    const float Tt  = readlane_f(Tbuf, s);
                    const float ItK = It * SOCK;               // off-chain
                    const float base_a = fmaf(Tt, w1pa2, fmaf(It, w1pa1, bpa));
                    const float base_b = fmaf(Tt, w1pb2, fmaf(It, w1pb1, bpb));
                    const float carry = socv;

                    // hidden layer (socv enters with ONE fma each)
                    const float ha = tanh_ps(fmaf(socv, w1pa0, base_a));
                    const float hb = tanh_ps(fmaf(socv, w1pb0, base_b));

                    // chain-3 (Q) partial + full 64-lane DPP sum -> lane 63
                    float z = fmaf(hb, w2pb3, ha * w2pa3);
                    z = dpp_add<0x111, 0xF>(z);
                    z = dpp_add<0x112, 0xF>(z);
                    z = dpp_add<0x114, 0xF>(z);
                    z = dpp_add<0x118, 0xF>(z);
                    z = dpp_add<0x142, 0xA>(z);
                    z = dpp_add<0x143, 0xC>(z);

                    // softplus (log2 domain) -> Q -> invQ
                    const float e  = __builtin_amdgcn_exp2f(z + biasQ);
                    const float lg = __builtin_amdgcn_logf(e + 1.0f);
                    const float Q  = fmaf(lg, 5.0f*LN2, EPSP);
                    const float invQ = readlane_f(__builtin_amdgcn_rcpf(Q), 63);

                    // soc update
                    socv = __builtin_amdgcn_fmed3f(fmaf(ItK, invQ, socv), 0.0f, 1.0f);

                    // hand-off gather (lane s keeps step-s values)
                    const bool m = (lane == s);
                    hand.x = m ? carry : hand.x;
                    hand.y = m ? socv  : hand.y;
                }
                handBuf[c & 1][lane] = hand;
            }
        } else {
            if (c == 0) {
                // prologue: stage weights to LDS (pre-scaled)
                pcoefS[lane]    = make_float4(W1p[0*HIDN+lane]*K2, W1p[1*HIDN+lane]*K2,
                                              W1p[2*HIDN+lane]*K2, b1p[lane]*K2);
                pcoefS[lane+64] = make_float4(W1p[0*HIDN+lane+64]*K2, W1p[1*HIDN+lane+64]*K2,
                                              W1p[2*HIDN+lane+64]*K2, b1p[lane+64]*K2);
                poutS[lane]     = make_float4(W2p[lane*4+0]*KL, W2p[lane*4+1]*KL,
                                              W2p[lane*4+2]*KL, 0.f);
                poutS[lane+64]  = make_float4(W2p[(lane+64)*4+0]*KL, W2p[(lane+64)*4+1]*KL,
                                              W2p[(lane+64)*4+2]*KL, 0.f);
                rcoefS[lane] = make_float4(W1r[0*64+lane]*K2, W1r[1*64+lane]*K2,
                                           W1r[2*64+lane]*K2, b1r[lane]*K2);
                w2rS[lane] = W2r[lane];
            } else {
                const int cc = c - 1;
                const float2 h = handBuf[cc & 1][lane];
                const float carry = h.x;     // soc at step entry (MLP input)
                const float post  = h.y;     // soc after update (OCV input)
                const float Is = Ib[cc * 64 + lane];
                const float Ts = Tb[cc * 64 + lane];

                // ---- param MLP (R0,R1,C1 only), per-lane dot products ----
                float aR0 = bias0, aR1 = bias1, aC1 = bias2;
                #pragma unroll 4
                for (int j = 0; j < 128; ++j) {
                    const float4 cj = pcoefS[j];  // uniform -> LDS broadcast
                    const float4 oj = poutS[j];
                    const float hj = tanh_ps(fmaf(Ts, cj.z, fmaf(Is, cj.y,
                                             fmaf(carry, cj.x, cj.w))));
                    aR0 = fmaf(hj, oj.x, aR0);
                    aR1 = fmaf(hj, oj.y, aR1);
                    aC1 = fmaf(hj, oj.z, aC1);
                }
                const float R0 = fmaf(__builtin_amdgcn_logf(
                                      __builtin_amdgcn_exp2f(aR0) + 1.0f), 0.01f*LN2, EPSP);
                const float R1 = fmaf(__builtin_amdgcn_logf(
                                      __builtin_amdgcn_exp2f(aR1) + 1.0f), 0.02f*LN2, EPSP);
                const float C1 = fmaf(__builtin_amdgcn_logf(
                                      __builtin_amdgcn_exp2f(aC1) + 1.0f), 2000.0f*LN2, EPSP);
                const float invC1   = __builtin_amdgcn_rcpf(C1);
                const float invR1C1 = __builtin_amdgcn_rcpf(R1) * invC1;

                // ---- v1 linear-recurrence scan: v1' = A_*v1c + B_ ----
                float A_ = 1.0f - invR1C1;
                float B_ = Is * invC1;
                #pragma unroll
                for (int d = 1; d < 64; d <<= 1) {
                    float Au = __shfl_up(A_, d);
                    float Bu = __shfl_up(B_, d);
                    const bool ok = (lane >= d);
                    Au = ok ? Au : 1.0f;          // identity transform
                    Bu = ok ? Bu : 0.0f;
                    const float Bn = fmaf(A_, Bu, B_);
                    A_ = A_ * Au;
                    B_ = Bn;
                }
                const float v1n = fmaf(A_, v1c, B_);   // v1 AFTER this lane's step
                v1c = readlane_f(v1n, 63);             // carry to next chunk

                // ---- resid MLP (per-lane dot product) ----
                float acc = b2rr;
                #pragma unroll 4
                for (int j = 0; j < 64; ++j) {
                    const float4 rj = rcoefS[j];
                    acc = fmaf(tanh_ps(fmaf(Ts, rj.z, fmaf(Is, rj.y,
                               fmaf(carry, rj.x, rj.w)))), w2rS[j], acc);
                }

                // ---- assembly ----
                const float ocv = fmaf(post, fmaf(post, fmaf(post, 0.3f, -0.5f), 1.2f), 3.0f);
                const float Vp  = (fmaf(-Is, R0, ocv) - v1n) + acc;
                Ob[cc * 64 + lane] = Vp;
            }
        }
        __syncthreads();
    }
}

extern "C" void kernel_launch(void* const* d_in, const int* in_sizes, int n_in,
                              void* d_out, int out_size, void* d_ws, size_t ws_size,
                              hipStream_t stream) {
    // setup_inputs order: V(0, unused), I(1), Tz(2), soc0(3),
    // W1p(4), b1p(5), W2p(6), b2p(7), W1r(8), b1r(9), W2r(10), b2r(11)
    const float* Iin  = (const float*)d_in[1];
    const float* Tzin = (const float*)d_in[2];
    const float* soc0 = (const float*)d_in[3];
    const float* W1p  = (const float*)d_in[4];
    const float* b1p  = (const float*)d_in[5];
    const float* W2p  = (const float*)d_in[6];
    const float* b2p  = (const float*)d_in[7];
    const float* W1r  = (const float*)d_in[8];
    const float* b1r  = (const float*)d_in[9];
    const float* W2r  = (const float*)d_in[10];
    const float* b2r  = (const float*)d_in[11];
    float* out = (float*)d_out;

    hipLaunchKernelGGL(rollout_kernel, dim3(NB), dim3(128), 0, stream,
                       Iin, Tzin, soc0, W1p, b1p, W2p, b2p, W1r, b1r, W2r, b2r, out);
}